// Round 4
// baseline (61.759 us; speedup 1.0000x reference)
//
#include <hip/hip_runtime.h>
#include <math.h>

#define EPS 1e-6f

// Input: feat_map [T=32][D=256][H=56][W=56] fp32 (d-slice = 3136 floats = 784 float4)
//
// loc_reduce: grid = 32 t * 16 dg = 512 blocks (2/CU), 832 threads (784 active).
//   Thread tid<784 owns fixed (h = tid/14, v = tid%14); walks 16 d-slices with an
//   explicit 4+4 ping-pong load pipeline (>=4 float4 loads in flight per wave at all
//   times) and register accumulation. Epilogue: LDS-atomic reduce to 4x56 partials,
//   disjoint ws stores (no global atomics, no memset).
//
// ws partials: [block=(t*16+dg)][arr(0:s1h,1:s2h,2:s1w,3:s2w)][56]  (114688 floats)
// out layout: [0]=tot, then log10(ga1)[32*56], ga2, ga3, ga4.

__global__ __launch_bounds__(832) void loc_reduce(const float* __restrict__ f,
                                                  float* __restrict__ ws) {
    const int t   = blockIdx.x >> 4;
    const int dg  = blockIdx.x & 15;
    const int tid = threadIdx.x;

    __shared__ float ls[224];  // [arr][56]
    for (int k = tid; k < 224; k += 832) ls[k] = 0.f;

    float s10 = 0.f, s11 = 0.f, s12 = 0.f, s13 = 0.f;
    float s20 = 0.f, s21 = 0.f, s22 = 0.f, s23 = 0.f;
    int h = 0, v = 0;

    if (tid < 784) {
        h = tid / 14;
        v = tid % 14;
        const float4* p4 = reinterpret_cast<const float4*>(
            f + (size_t)t * 802816 + (size_t)(dg * 16) * 3136) + (size_t)h * 14 + v;

        float4 xa[4], xb[4];
        #pragma unroll
        for (int u = 0; u < 4; ++u) xa[u] = p4[(size_t)u * 784];

#define ACC4(B)                                                        \
        do {                                                           \
            _Pragma("unroll")                                          \
            for (int u = 0; u < 4; ++u) {                              \
                s10 += (B)[u].x; s11 += (B)[u].y;                      \
                s12 += (B)[u].z; s13 += (B)[u].w;                      \
                s20 += (B)[u].x * (B)[u].x; s21 += (B)[u].y * (B)[u].y;\
                s22 += (B)[u].z * (B)[u].z; s23 += (B)[u].w * (B)[u].w;\
            }                                                          \
        } while (0)

        // batch 1 loads, consume batch 0; etc. (always >=4 in flight)
        #pragma unroll
        for (int u = 0; u < 4; ++u) xb[u] = p4[(size_t)(4 + u) * 784];
        ACC4(xa);
        #pragma unroll
        for (int u = 0; u < 4; ++u) xa[u] = p4[(size_t)(8 + u) * 784];
        ACC4(xb);
        #pragma unroll
        for (int u = 0; u < 4; ++u) xb[u] = p4[(size_t)(12 + u) * 784];
        ACC4(xa);
        ACC4(xb);
#undef ACC4
    }

    __syncthreads();   // LDS zero-init complete before atomics

    if (tid < 784) {
        atomicAdd(&ls[0 * 56 + h], s10 + s11 + s12 + s13);
        atomicAdd(&ls[1 * 56 + h], s20 + s21 + s22 + s23);
        atomicAdd(&ls[2 * 56 + 4 * v + 0], s10);
        atomicAdd(&ls[2 * 56 + 4 * v + 1], s11);
        atomicAdd(&ls[2 * 56 + 4 * v + 2], s12);
        atomicAdd(&ls[2 * 56 + 4 * v + 3], s13);
        atomicAdd(&ls[3 * 56 + 4 * v + 0], s20);
        atomicAdd(&ls[3 * 56 + 4 * v + 1], s21);
        atomicAdd(&ls[3 * 56 + 4 * v + 2], s22);
        atomicAdd(&ls[3 * 56 + 4 * v + 3], s23);
    }
    __syncthreads();

    if (tid < 224) ws[(size_t)blockIdx.x * 224 + tid] = ls[tid];
}

__global__ __launch_bounds__(1024) void loc_finalize(const float* __restrict__ ws,
                                                     float* __restrict__ out) {
    __shared__ float sums[7168];  // [t][arr][56] = 28 KB
    const int tid = threadIdx.x;

    #pragma unroll
    for (int k = 0; k < 7; ++k) {
        const int o = tid + 1024 * k;       // o = (t*4 + arr)*56 + i
        const int t = o / 224;
        const int r = o % 224;
        float a = 0.f;
        #pragma unroll
        for (int dg = 0; dg < 16; ++dg) a += ws[(size_t)(t * 16 + dg) * 224 + r];
        sums[o] = a;
    }
    __syncthreads();

    if (tid < 64) {
        const int t    = tid & 31;
        const bool isW = tid >= 32;

        const float* s1 = &sums[(t * 4 + (isW ? 2 : 0)) * 56];
        const float* s2 = &sums[(t * 4 + (isW ? 3 : 1)) * 56];
        float* osuf = out + 1 + (isW ? 3584 : 0)    + t * 56;  // ga1 / ga3
        float* opre = out + 1 + (isW ? 5376 : 1792) + t * 56;  // ga2 / ga4

        const float n_per = 14336.f;  // D*W == D*H
        float part = 0.f;

        float a1 = 0.f, a2 = 0.f;
        for (int i = 55; i >= 0; --i) {            // suffix
            a1 += s1[i]; a2 += s2[i];
            const float n  = n_per * (float)(56 - i);
            const float ga = sqrtf(a2 + 2.0f * EPS * a1 + (EPS * EPS) * n);
            osuf[i] = log10f(ga);
            part += ga + EPS;
        }
        a1 = 0.f; a2 = 0.f;
        for (int i = 0; i < 56; ++i) {             // prefix
            a1 += s1[i]; a2 += s2[i];
            const float n  = n_per * (float)(i + 1);
            const float ga = sqrtf(a2 + 2.0f * EPS * a1 + (EPS * EPS) * n);
            opre[i] = log10f(ga);
            part += ga + EPS;
        }

        #pragma unroll
        for (int off = 32; off; off >>= 1) part += __shfl_down(part, off);
        if (tid == 0) out[0] = part * (1.0f / 128.0f);  // /T /4
    }
}

extern "C" void kernel_launch(void* const* d_in, const int* in_sizes, int n_in,
                              void* d_out, int out_size, void* d_ws, size_t ws_size,
                              hipStream_t stream) {
    const float* f = (const float*)d_in[0];
    float* out = (float*)d_out;
    float* ws  = (float*)d_ws;

    loc_reduce<<<dim3(512), dim3(832), 0, stream>>>(f, ws);
    loc_finalize<<<dim3(1), dim3(1024), 0, stream>>>(ws, out);
}